// Round 1
// baseline (57.446 us; speedup 1.0000x reference)
//
#include <hip/hip_runtime.h>

// Problem constants (AdaptivePruner)
#define NB   256   // batch
#define NTOK 197   // tokens incl cls
#define NP   196   // patch tokens
#define ND   768   // channels
#define LEN1 101   // one-level DWT length
#define LEN2 54    // two-level DWT length
#define OUTROWS 102
#define NSPLIT 4   // token-axis segments per column (occupancy)

__device__ __forceinline__ float4 fma4(float a, float4 b, float4 c) {
    return make_float4(fmaf(a, b.x, c.x), fmaf(a, b.y, c.y),
                       fmaf(a, b.z, c.z), fmaf(a, b.w, c.w));
}

// ---------------- Gini kernel: one block per batch row ----------------
// gini = 2*sum(rank_i * p_i)/(N*sum(p) + 1e-8) - (N+1)/N, rank = ascending 1-based.
// Rank computed by counting (tie-order irrelevant to the weighted sum).
// Double accumulation -> exact value, robust at the 0.333 boundary.
__global__ __launch_bounds__(256)
void gini_kernel(const float* __restrict__ attn, int* __restrict__ flags) {
    __shared__ float  row[NP];
    __shared__ double sS[256];
    __shared__ double sT[256];
    const int b   = blockIdx.x;
    const int tid = threadIdx.x;
    if (tid < NP) row[tid] = attn[b * NP + tid];
    __syncthreads();
    double sj = 0.0, tj = 0.0;
    if (tid < NP) {
        const float p = row[tid];
        int rank = 1;
        for (int k = 0; k < NP; ++k) {
            const float q = row[k];
            rank += (q < p) || (q == p && k < tid);
        }
        sj = (double)rank * (double)p;
        tj = (double)p;
    }
    sS[tid] = sj; sT[tid] = tj;
    __syncthreads();
    for (int off = 128; off > 0; off >>= 1) {
        if (tid < off) { sS[tid] += sS[tid + off]; sT[tid] += sT[tid + off]; }
        __syncthreads();
    }
    if (tid == 0) {
        const double S = sS[0], T = sT[0];
        const double gini = 2.0 * S / ((double)NP * T + 1e-8)
                          - (double)(NP + 1) / (double)NP;
        flags[b] = (gini > (double)0.333f) ? 1 : 0;
    }
}

// ---------------- Main DWT kernel ----------------
// One thread per float4 channel column, NSPLIT token segments.
// gid = ((b*NSPLIT + seg)*192) + c ; wave (64 lanes) = consecutive c -> uniform b,seg.
__global__ __launch_bounds__(256)
void dwt_kernel(const float* __restrict__ x, const int* __restrict__ flags,
                float* __restrict__ out_x, float* __restrict__ out_mask) {
    const int gid = blockIdx.x * blockDim.x + threadIdx.x;
    const int c   = gid % 192;
    const int bs  = gid / 192;
    const int seg = bs % NSPLIT;
    const int b   = bs / NSPLIT;
    if (b >= NB) return;

    const float h[8] = {0.23037781330885523f,  0.7148465705525415f,
                        0.6308807679295904f,  -0.02798376941698385f,
                       -0.18703481171888114f,  0.030841381835986965f,
                        0.032883011666982945f,-0.010597401784997278f};

    const int d0 = c * 4;
    const float* __restrict__ px = x + ((size_t)b * NTOK + 1) * ND + d0; // patch[0] base
    float* __restrict__ po = out_x + (size_t)b * OUTROWS * ND + d0;
    const int flag = flags[b];

    // cls passthrough + mask (seg 0 only)
    if (seg == 0) {
        const float4 cls = *(const float4*)(x + (size_t)b * NTOK * ND + d0);
        *(float4*)po = cls;
        if (c < OUTROWS) {
            const int outlen = flag ? LEN2 : LEN1;
            out_mask[b * OUTROWS + c] =
                (c == 0 || (c - 1) < outlen) ? 1.0f : 0.0f;
        }
    }

    auto loadx = [&](int i) -> float4 {
        if (i < 0 || i >= NP) return make_float4(0.f, 0.f, 0.f, 0.f);
        return *(const float4*)(px + (size_t)i * ND);
    };

    if (!flag) {
        // ---- one-level: y1[t] = sum_l xp(2t-6+l)*h[l], t in [t0,t1) ----
        const int chunk = (LEN1 + NSPLIT - 1) / NSPLIT;   // 26
        const int t0 = seg * chunk;
        const int t1 = min(LEN1, t0 + chunk);
        float4 w[8];
        #pragma unroll
        for (int l = 0; l < 8; ++l) w[l] = loadx(2 * t0 - 6 + l);
        for (int t = t0; t < t1; ++t) {
            float4 y = make_float4(0.f, 0.f, 0.f, 0.f);
            #pragma unroll
            for (int l = 0; l < 8; ++l) y = fma4(h[l], w[l], y);
            *(float4*)(po + (size_t)(1 + t) * ND) = y;
            #pragma unroll
            for (int l = 0; l < 6; ++l) w[l] = w[l + 2];
            w[6] = loadx(2 * t + 2);
            w[7] = loadx(2 * t + 3);
        }
    } else {
        // ---- two-level cascade: y2[s] for s in [s0,s1), then zero rows ----
        const int schunk = (LEN2 + NSPLIT - 1) / NSPLIT;  // 14
        const int s0 = seg * schunk;
        const int s1 = min(LEN2, s0 + schunk);
        float4 v[8];
        #pragma unroll
        for (int l = 0; l < 8; ++l) v[l] = make_float4(0.f, 0.f, 0.f, 0.f);
        const int tstart = 2 * s0 - 6;
        float4 w[8];
        #pragma unroll
        for (int l = 0; l < 8; ++l) w[l] = loadx(2 * tstart - 6 + l);
        for (int t = tstart; t < 2 * s1; ++t) {
            // z = y1p(t): y1[t] for 0<=t<101, else 0 (covers odd-length end pad)
            float4 z = make_float4(0.f, 0.f, 0.f, 0.f);
            if (t >= 0 && t < LEN1) {
                #pragma unroll
                for (int l = 0; l < 8; ++l) z = fma4(h[l], w[l], z);
            }
            #pragma unroll
            for (int l = 0; l < 7; ++l) v[l] = v[l + 1];
            v[7] = z;
            if ((t & 1) == 1 && t >= 1) {
                const int s = (t - 1) >> 1;
                if (s >= s0) {
                    float4 y = make_float4(0.f, 0.f, 0.f, 0.f);
                    #pragma unroll
                    for (int l = 0; l < 8; ++l) y = fma4(h[l], v[l], y);
                    *(float4*)(po + (size_t)(1 + s) * ND) = y;
                }
            }
            #pragma unroll
            for (int l = 0; l < 6; ++l) w[l] = w[l + 2];
            w[6] = loadx(2 * t + 2);
            w[7] = loadx(2 * t + 3);
        }
        // zero-fill rows [LEN2, LEN1) of final_patches, split across segs
        const int zchunk = (LEN1 - LEN2 + NSPLIT - 1) / NSPLIT; // 12
        const int r0 = LEN2 + seg * zchunk;
        const int r1 = min(LEN1, r0 + zchunk);
        const float4 zero = make_float4(0.f, 0.f, 0.f, 0.f);
        for (int r = r0; r < r1; ++r)
            *(float4*)(po + (size_t)(1 + r) * ND) = zero;
    }
}

extern "C" void kernel_launch(void* const* d_in, const int* in_sizes, int n_in,
                              void* d_out, int out_size, void* d_ws, size_t ws_size,
                              hipStream_t stream) {
    const float* x    = (const float*)d_in[0];  // (256,197,768) f32
    const float* attn = (const float*)d_in[1];  // (256,196) f32
    float* out_x    = (float*)d_out;                         // (256,102,768)
    float* out_mask = (float*)d_out + (size_t)NB * OUTROWS * ND; // (256,102) as 0/1 f32
    int* flags = (int*)d_ws;                                 // 256 ints

    gini_kernel<<<NB, 256, 0, stream>>>(attn, flags);

    const int total = NB * NSPLIT * 192;   // 196608 threads
    dwt_kernel<<<total / 256, 256, 0, stream>>>(x, flags, out_x, out_mask);
}

// Round 2
// 51.601 us; speedup vs baseline: 1.1133x; 1.1133x over previous
//
#include <hip/hip_runtime.h>

// Problem constants (AdaptivePruner)
#define NB   256   // batch
#define NTOK 197   // tokens incl cls
#define NP   196   // patch tokens
#define ND   768   // channels
#define LEN1 101   // one-level DWT length
#define LEN2 54    // two-level DWT length
#define OUTROWS 102
#define NWG (NB * OUTROWS)   // 26112, divisible by 8

typedef float f4 __attribute__((ext_vector_type(4)));

// ---------------- Gini kernel: one block per batch row ----------------
// gini = 2*sum(rank_i * p_i)/(N*sum(p) + 1e-8) - (N+1)/N, rank = ascending 1-based.
// Rank computed by counting (tie-order irrelevant to the weighted sum).
// Double accumulation -> exact value, robust at the 0.333 boundary.
__global__ __launch_bounds__(256)
void gini_kernel(const float* __restrict__ attn, int* __restrict__ flags) {
    __shared__ float  row[NP];
    __shared__ double sS[256];
    __shared__ double sT[256];
    const int b   = blockIdx.x;
    const int tid = threadIdx.x;
    if (tid < NP) row[tid] = attn[b * NP + tid];
    __syncthreads();
    double sj = 0.0, tj = 0.0;
    if (tid < NP) {
        const float p = row[tid];
        int rank = 1;
        for (int k = 0; k < NP; ++k) {
            const float q = row[k];
            rank += (q < p) || (q == p && k < tid);
        }
        sj = (double)rank * (double)p;
        tj = (double)p;
    }
    sS[tid] = sj; sT[tid] = tj;
    __syncthreads();
    for (int off = 128; off > 0; off >>= 1) {
        if (tid < off) { sS[tid] += sS[tid + off]; sT[tid] += sT[tid + off]; }
        __syncthreads();
    }
    if (tid == 0) {
        const double S = sS[0], T = sT[0];
        const double gini = 2.0 * S / ((double)NP * T + 1e-8)
                          - (double)(NP + 1) / (double)NP;
        flags[b] = (gini > (double)0.333f) ? 1 : 0;
    }
}

// ---------------- Main DWT kernel ----------------
// One block (192 threads = 3 waves) per output row (b, r). Each thread owns
// one float4 channel group. All taps loaded independently (full MLP).
// Two-level case uses the composite 22-tap stride-4 filter (cascade collapsed).
__global__ __launch_bounds__(192)
void dwt_kernel(const float* __restrict__ x, const int* __restrict__ flags,
                float* __restrict__ out_x, float* __restrict__ out_mask) {
    const float h[8] = {0.23037781330885523f,  0.7148465705525415f,
                        0.6308807679295904f,  -0.02798376941698385f,
                       -0.18703481171888114f,  0.030841381835986965f,
                        0.032883011666982945f,-0.010597401784997278f};
    // composite two-level filter g[m] = sum_{2j+l=m} h[j]*h[l]  (constant-folded)
    float g[22];
    #pragma unroll
    for (int m = 0; m < 22; ++m) {
        float s = 0.f;
        #pragma unroll
        for (int j = 0; j < 8; ++j) {
            const int l = m - 2 * j;
            if (0 <= l && l < 8) s += h[j] * h[l];
        }
        g[m] = s;
    }

    // XCD-aware bijective swizzle: XCD k gets contiguous logical chunk.
    const int hw  = blockIdx.x;
    const int per = NWG / 8;                  // 3264
    const int bid = (hw & 7) * per + (hw >> 3);
    const int b = bid / OUTROWS;
    const int r = bid - b * OUTROWS;
    const int c = threadIdx.x;                // 0..191 channel float4 group
    const int d0 = c * 4;

    const float* __restrict__ px = x + ((size_t)b * NTOK + 1) * ND + d0; // patch[0]
    float* __restrict__ po = out_x + ((size_t)b * OUTROWS + r) * ND + d0;
    const int flag = flags[b];

    if (r == 0) {
        // cls passthrough + mask
        const f4 cls = *(const f4*)(x + (size_t)b * NTOK * ND + d0);
        __builtin_nontemporal_store(cls, (f4*)po);
        if (c < OUTROWS) {
            const int outlen = flag ? LEN2 : LEN1;
            out_mask[b * OUTROWS + c] = (c == 0 || (c - 1) < outlen) ? 1.0f : 0.0f;
        }
        return;
    }

    const int t = r - 1;                      // 0..100
    f4 y = {0.f, 0.f, 0.f, 0.f};
    if (!flag) {
        // one-level: y1[t] = sum_l h[l] * xp(2t-6+l)
        const int base = 2 * t - 6;
        #pragma unroll
        for (int l = 0; l < 8; ++l) {
            const int i = base + l;           // block-uniform -> scalar branch
            if (i >= 0 && i < NP) {
                const f4 v = *(const f4*)(px + (size_t)i * ND);
                y += h[l] * v;
            }
        }
    } else if (t < LEN2) {
        // two-level composite: y2[t] = sum_m g[m] * xp(4t-18+m)
        const int base = 4 * t - 18;
        #pragma unroll
        for (int m = 0; m < 22; ++m) {
            const int i = base + m;
            if (i >= 0 && i < NP) {
                const f4 v = *(const f4*)(px + (size_t)i * ND);
                y += g[m] * v;
            }
        }
    }
    // (flag && t >= LEN2) -> zero row (pad region)
    __builtin_nontemporal_store(y, (f4*)po);
}

extern "C" void kernel_launch(void* const* d_in, const int* in_sizes, int n_in,
                              void* d_out, int out_size, void* d_ws, size_t ws_size,
                              hipStream_t stream) {
    const float* x    = (const float*)d_in[0];  // (256,197,768) f32
    const float* attn = (const float*)d_in[1];  // (256,196) f32
    float* out_x    = (float*)d_out;                             // (256,102,768)
    float* out_mask = (float*)d_out + (size_t)NB * OUTROWS * ND; // (256,102)
    int* flags = (int*)d_ws;                                     // 256 ints

    gini_kernel<<<NB, 256, 0, stream>>>(attn, flags);
    dwt_kernel<<<NWG, 192, 0, stream>>>(x, flags, out_x, out_mask);
}

// Round 3
// 44.352 us; speedup vs baseline: 1.2952x; 1.1635x over previous
//
#include <hip/hip_runtime.h>

// Problem constants (AdaptivePruner)
#define NB   256   // batch
#define NTOK 197   // tokens incl cls
#define NP   196   // patch tokens
#define ND   768   // channels
#define LEN1 101   // one-level DWT length
#define LEN2 54    // two-level DWT length
#define OUTROWS 102
#define NGRP 51               // row-pairs per batch (102 rows / 2)
#define NWG  (NB * NGRP)      // 13056, divisible by 8

typedef float f4 __attribute__((ext_vector_type(4)));

// ---------------- Gini kernel: one block per batch row ----------------
// gini = 2*sum(rank_i*p_i)/(N*sum(p)+1e-8) - (N+1)/N, rank ascending 1-based.
// Rank by counting (tie-order irrelevant to the sum); double accumulation.
__global__ __launch_bounds__(256)
void gini_kernel(const float* __restrict__ attn, int* __restrict__ flags) {
    __shared__ float  row[NP];
    __shared__ double sS[256];
    __shared__ double sT[256];
    const int b   = blockIdx.x;
    const int tid = threadIdx.x;
    if (tid < NP) row[tid] = attn[b * NP + tid];
    __syncthreads();
    double sj = 0.0, tj = 0.0;
    if (tid < NP) {
        const float p = row[tid];
        int rank = 1;
        for (int k = 0; k < NP; ++k) {
            const float q = row[k];
            rank += (q < p) || (q == p && k < tid);
        }
        sj = (double)rank * (double)p;
        tj = (double)p;
    }
    sS[tid] = sj; sT[tid] = tj;
    __syncthreads();
    for (int off = 128; off > 0; off >>= 1) {
        if (tid < off) { sS[tid] += sS[tid + off]; sT[tid] += sT[tid + off]; }
        __syncthreads();
    }
    if (tid == 0) {
        const double S = sS[0], T = sT[0];
        const double gini = 2.0 * S / ((double)NP * T + 1e-8)
                          - (double)(NP + 1) / (double)NP;
        flags[b] = (gini > (double)0.333f) ? 1 : 0;
    }
}

// ---------------- Main DWT kernel ----------------
// One block (192 threads) per output ROW-PAIR (b, rows 2g & 2g+1).
// Each thread owns one float4 channel group; shared register window per pair.
__global__ __launch_bounds__(192)
void dwt_kernel(const float* __restrict__ x, const int* __restrict__ flags,
                float* __restrict__ out_x, float* __restrict__ out_mask) {
    const float h[8] = {0.23037781330885523f,  0.7148465705525415f,
                        0.6308807679295904f,  -0.02798376941698385f,
                       -0.18703481171888114f,  0.030841381835986965f,
                        0.032883011666982945f,-0.010597401784997278f};
    // composite two-level filter g2[m] = sum_{2j+l=m} h[j]*h[l] (constant-folded)
    float g2[22];
    #pragma unroll
    for (int m = 0; m < 22; ++m) {
        float s = 0.f;
        #pragma unroll
        for (int j = 0; j < 8; ++j) {
            const int l = m - 2 * j;
            if (0 <= l && l < 8) s += h[j] * h[l];
        }
        g2[m] = s;
    }

    // XCD-aware bijective swizzle (NWG % 8 == 0)
    const int hw  = blockIdx.x;
    const int per = NWG / 8;                 // 1632
    const int bid = (hw & 7) * per + (hw >> 3);
    const int b   = bid / NGRP;
    const int grp = bid - b * NGRP;          // 0..50
    const int c   = threadIdx.x;             // channel float4 group
    const int d0  = c * 4;

    const float* __restrict__ px = x + ((size_t)b * NTOK + 1) * ND + d0; // patch[0]
    float* __restrict__ po = out_x + (size_t)b * OUTROWS * ND + d0;
    const int flag = flags[b];

    auto loadx = [&](int i) -> f4 {
        if (i < 0 || i >= NP) return (f4){0.f, 0.f, 0.f, 0.f};
        return *(const f4*)(px + (size_t)i * ND);
    };

    if (grp == 0) {
        // row 0: cls passthrough (+ mask), row 1: first output row
        const f4 cls = *(const f4*)(x + (size_t)b * NTOK * ND + d0);
        __builtin_nontemporal_store(cls, (f4*)po);
        if (c < OUTROWS) {
            const int outlen = flag ? LEN2 : LEN1;
            out_mask[b * OUTROWS + c] = (c == 0 || (c - 1) < outlen) ? 1.0f : 0.0f;
        }
        f4 y = {0.f, 0.f, 0.f, 0.f};
        if (!flag) {
            // t=0: i = -6+l, valid l=6,7 -> i=0,1
            y += h[6] * loadx(0);
            y += h[7] * loadx(1);
        } else {
            // s=0: i = -18+m, valid m=18..21 -> i=0..3
            #pragma unroll
            for (int m = 18; m < 22; ++m) y += g2[m] * loadx(m - 18);
        }
        __builtin_nontemporal_store(y, (f4*)(po + (size_t)ND));
        return;
    }

    if (!flag) {
        // rows 2g, 2g+1  <->  t0 = 2g-1, t1 = 2g ; window i in [4g-8, 4g+1]
        const int lo = 4 * grp - 8;
        f4 w[10];
        if (grp >= 2 && grp <= 48) {
            #pragma unroll
            for (int k = 0; k < 10; ++k) w[k] = *(const f4*)(px + (size_t)(lo + k) * ND);
        } else {
            #pragma unroll
            for (int k = 0; k < 10; ++k) w[k] = loadx(lo + k);
        }
        f4 y0 = {0.f,0.f,0.f,0.f}, y1 = {0.f,0.f,0.f,0.f};
        #pragma unroll
        for (int l = 0; l < 8; ++l) {
            y0 += h[l] * w[l];
            y1 += h[l] * w[l + 2];
        }
        __builtin_nontemporal_store(y0, (f4*)(po + (size_t)(2 * grp) * ND));
        __builtin_nontemporal_store(y1, (f4*)(po + (size_t)(2 * grp + 1) * ND));
    } else {
        const int s0 = 2 * grp - 1;          // rows 2g (=1+s0), 2g+1 (=1+s0+1)
        if (s0 < LEN2) {
            // window i in [4*s0-18, 4*s0+7] = [8g-22, 8g+3], 26 rows
            const int lo = 8 * grp - 22;
            f4 w[26];
            if (grp >= 3 && grp <= 24) {
                #pragma unroll
                for (int k = 0; k < 26; ++k) w[k] = *(const f4*)(px + (size_t)(lo + k) * ND);
            } else {
                #pragma unroll
                for (int k = 0; k < 26; ++k) w[k] = loadx(lo + k);
            }
            f4 y0 = {0.f,0.f,0.f,0.f}, y1 = {0.f,0.f,0.f,0.f};
            #pragma unroll
            for (int m = 0; m < 22; ++m) {
                y0 += g2[m] * w[m];
                y1 += g2[m] * w[m + 4];
            }
            if (s0 + 1 >= LEN2) y1 = (f4){0.f,0.f,0.f,0.f};   // row 55 is pad
            __builtin_nontemporal_store(y0, (f4*)(po + (size_t)(2 * grp) * ND));
            __builtin_nontemporal_store(y1, (f4*)(po + (size_t)(2 * grp + 1) * ND));
        } else {
            const f4 zero = {0.f,0.f,0.f,0.f};
            __builtin_nontemporal_store(zero, (f4*)(po + (size_t)(2 * grp) * ND));
            __builtin_nontemporal_store(zero, (f4*)(po + (size_t)(2 * grp + 1) * ND));
        }
    }
}

extern "C" void kernel_launch(void* const* d_in, const int* in_sizes, int n_in,
                              void* d_out, int out_size, void* d_ws, size_t ws_size,
                              hipStream_t stream) {
    const float* x    = (const float*)d_in[0];  // (256,197,768) f32
    const float* attn = (const float*)d_in[1];  // (256,196) f32
    float* out_x    = (float*)d_out;                             // (256,102,768)
    float* out_mask = (float*)d_out + (size_t)NB * OUTROWS * ND; // (256,102)
    int* flags = (int*)d_ws;                                     // 256 ints

    gini_kernel<<<NB, 256, 0, stream>>>(attn, flags);
    dwt_kernel<<<NWG, 192, 0, stream>>>(x, flags, out_x, out_mask);
}